// Round 11
// baseline (2159.196 us; speedup 1.0000x reference)
//
#include <hip/hip_runtime.h>

#define NPTS 4096
#define NB 4
#define KNN 20
#define NCAND 64
#define RANKT 32
#define MROWS (NB*NPTS)

#define NBIN 1024
#define NSUB 8
#define HPITCH 1028
#define HISTN (NSUB*HPITCH)   // 8224 ints = 32.9 KB

__device__ __forceinline__ float lrelu(float v) { return v >= 0.f ? v : 0.2f * v; }

__device__ __forceinline__ unsigned fkey(float f) {
  unsigned u = __float_as_uint(f);
  return (u & 0x80000000u) ? ~u : (u | 0x80000000u);
}
__device__ __forceinline__ float funkey(unsigned k) {
  unsigned u = (k & 0x80000000u) ? (k ^ 0x80000000u) : ~k;
  return __uint_as_float(u);
}

// deterministic C=3 key (explicit fma chain so every call site compiles identically)
__device__ __forceinline__ unsigned key3(float x0, float x1, float x2,
                                         const float* __restrict__ xm) {
  float d0 = x0 - xm[0];
  float d1 = x1 - xm[1];
  float d2 = x2 - xm[2];
  return fkey(-__fmaf_rn(d0, d0, __fmaf_rn(d1, d1, d2 * d2)));
}

// ---------------- squared norms (fp32) ----------------
__global__ __launch_bounds__(256) void sqnorm_k(const float* __restrict__ X, int ldx, int C,
                                                float* __restrict__ xx) {
  int r = blockIdx.x * 256 + threadIdx.x;
  if (r >= MROWS) return;
  const float* row = X + (size_t)r * ldx;
  float s = 0.f;
  for (int c = 0; c < C; ++c) { float v = row[c]; s += v * v; }
  xx[r] = s;
}

// ---------------- unified 128x128 fp32 GEMM (value mode / dist mode) ----------------
__global__ __launch_bounds__(256, 2) void gemm128_k(
    const float* __restrict__ A, int lda,
    const float* __restrict__ B, int ldb, int C,
    float* __restrict__ out, int ldo,
    const float* __restrict__ bias2d, int bstride,
    const float* __restrict__ xxa, const float* __restrict__ xxb) {
  __shared__ float As[32][128];
  __shared__ float Bs[32][128];
  int t = threadIdx.x;
  int tx = t & 15, ty = t >> 4;
  int mbase = blockIdx.x * 128;
  int rbase = blockIdx.y * 128;
  float acc[8][8] = {};
  int lr = t >> 1;
  int lk = (t & 1) * 16;
  const float* pa0 = A + (size_t)(rbase + lr) * lda + lk;
  const float* pb0 = B + (size_t)(mbase + lr) * ldb + lk;
  for (int kc = 0; kc < C; kc += 32) {
    const float* pa = pa0 + kc;
    const float* pb = pb0 + kc;
    #pragma unroll
    for (int j4 = 0; j4 < 4; ++j4) {
      float4 a4 = *(const float4*)(pa + j4 * 4);
      float4 b4 = *(const float4*)(pb + j4 * 4);
      As[lk + j4*4 + 0][lr] = a4.x;
      As[lk + j4*4 + 1][lr] = a4.y;
      As[lk + j4*4 + 2][lr] = a4.z;
      As[lk + j4*4 + 3][lr] = a4.w;
      Bs[lk + j4*4 + 0][lr] = b4.x;
      Bs[lk + j4*4 + 1][lr] = b4.y;
      Bs[lk + j4*4 + 2][lr] = b4.z;
      Bs[lk + j4*4 + 3][lr] = b4.w;
    }
    __syncthreads();
    #pragma unroll
    for (int k = 0; k < 32; ++k) {
      float4 a0 = ((const float4*)As[k])[ty];
      float4 a1 = ((const float4*)As[k])[16 + ty];
      float4 b0 = ((const float4*)Bs[k])[tx];
      float4 b1 = ((const float4*)Bs[k])[16 + tx];
      float av[8] = {a0.x,a0.y,a0.z,a0.w,a1.x,a1.y,a1.z,a1.w};
      float bv[8] = {b0.x,b0.y,b0.z,b0.w,b1.x,b1.y,b1.z,b1.w};
      #pragma unroll
      for (int i = 0; i < 8; ++i)
        #pragma unroll
        for (int j = 0; j < 8; ++j)
          acc[i][j] += av[i] * bv[j];
    }
    __syncthreads();
  }
  #pragma unroll
  for (int ih = 0; ih < 2; ++ih) {
    #pragma unroll
    for (int i4 = 0; i4 < 4; ++i4) {
      int i = ih * 4 + i4;
      int r = rbase + ih * 64 + ty * 4 + i4;
      float xr = xxa ? xxa[r] : 0.f;
      const float* brow = bias2d ? (bias2d + (size_t)(r >> 12) * bstride) : nullptr;
      #pragma unroll
      for (int jh = 0; jh < 2; ++jh) {
        float4 o4;
        #pragma unroll
        for (int j4 = 0; j4 < 4; ++j4) {
          int j = jh * 4 + j4;
          int m = mbase + jh * 64 + tx * 4 + j4;
          float val = acc[i][j];
          if (xxa) val = 2.f * val - xr - xxb[m];
          else if (brow) val += brow[m];
          (&o4.x)[j4] = val;
        }
        *(float4*)&out[(size_t)r * ldo + mbase + jh * 64 + tx * 4] = o4;
      }
    }
  }
}

// ---------------- symmetric-triangle distance GEMM (full batch, mirrored writes) ----------------
__global__ __launch_bounds__(256, 2) void dist_tri_k(const float* __restrict__ Xb, int ldx, int C,
                                                     const float* __restrict__ xxb,
                                                     float* __restrict__ D) {
  __shared__ float As[32][128];
  __shared__ float Bs[32][128];
  __shared__ float Ts[32][129];
  int t = threadIdx.x;
  int tx = t & 15, ty = t >> 4;
  int lin = blockIdx.x, bi = 0;
  while (lin >= 32 - bi) { lin -= 32 - bi; ++bi; }
  int bj = bi + lin;
  int rbase = bi * 128;
  int mbase = bj * 128;
  float acc[8][8] = {};
  int lr = t >> 1;
  int lk = (t & 1) * 16;
  const float* pa0 = Xb + (size_t)(rbase + lr) * ldx + lk;
  const float* pb0 = Xb + (size_t)(mbase + lr) * ldx + lk;
  for (int kc = 0; kc < C; kc += 32) {
    const float* pa = pa0 + kc;
    const float* pb = pb0 + kc;
    #pragma unroll
    for (int j4 = 0; j4 < 4; ++j4) {
      float4 a4 = *(const float4*)(pa + j4 * 4);
      float4 b4 = *(const float4*)(pb + j4 * 4);
      As[lk + j4*4 + 0][lr] = a4.x;
      As[lk + j4*4 + 1][lr] = a4.y;
      As[lk + j4*4 + 2][lr] = a4.z;
      As[lk + j4*4 + 3][lr] = a4.w;
      Bs[lk + j4*4 + 0][lr] = b4.x;
      Bs[lk + j4*4 + 1][lr] = b4.y;
      Bs[lk + j4*4 + 2][lr] = b4.z;
      Bs[lk + j4*4 + 3][lr] = b4.w;
    }
    __syncthreads();
    #pragma unroll
    for (int k = 0; k < 32; ++k) {
      float4 a0 = ((const float4*)As[k])[ty];
      float4 a1 = ((const float4*)As[k])[16 + ty];
      float4 b0 = ((const float4*)Bs[k])[tx];
      float4 b1 = ((const float4*)Bs[k])[16 + tx];
      float av[8] = {a0.x,a0.y,a0.z,a0.w,a1.x,a1.y,a1.z,a1.w};
      float bv[8] = {b0.x,b0.y,b0.z,b0.w,b1.x,b1.y,b1.z,b1.w};
      #pragma unroll
      for (int i = 0; i < 8; ++i)
        #pragma unroll
        for (int j = 0; j < 8; ++j)
          acc[i][j] += av[i] * bv[j];
    }
    __syncthreads();
  }
  #pragma unroll
  for (int ih = 0; ih < 2; ++ih) {
    #pragma unroll
    for (int i4 = 0; i4 < 4; ++i4) {
      int i = ih * 4 + i4;
      int r = rbase + ih * 64 + ty * 4 + i4;
      float xr = xxb[r];
      #pragma unroll
      for (int jh = 0; jh < 2; ++jh) {
        float4 o4;
        #pragma unroll
        for (int j4 = 0; j4 < 4; ++j4) {
          int j = jh * 4 + j4;
          int m = mbase + jh * 64 + tx * 4 + j4;
          float val = 2.f * acc[i][j] - xr - xxb[m];
          acc[i][j] = val;
          (&o4.x)[j4] = val;
        }
        *(float4*)&D[(size_t)r * NPTS + mbase + jh * 64 + tx * 4] = o4;
      }
    }
  }
  if (bi != bj) {
    #pragma unroll
    for (int g = 0; g < 4; ++g) {
      __syncthreads();
      #pragma unroll
      for (int jh = 0; jh < 2; ++jh) {
        int mlo = jh * 64 + tx * 4;
        if ((mlo >> 5) == g) {
          #pragma unroll
          for (int i = 0; i < 8; ++i) {
            int r_local = (i >> 2) * 64 + ty * 4 + (i & 3);
            #pragma unroll
            for (int j4 = 0; j4 < 4; ++j4)
              Ts[(mlo & 31) + j4][r_local] = acc[i][jh * 4 + j4];
          }
        }
      }
      __syncthreads();
      int rowg = t >> 3;
      int colb = (t & 7) * 16;
      int mg = mbase + g * 32 + rowg;
      float4* dst = (float4*)&D[(size_t)mg * NPTS + rbase + colb];
      #pragma unroll
      for (int q = 0; q < 4; ++q) {
        float4 vq;
        vq.x = Ts[rowg][colb + q*4 + 0];
        vq.y = Ts[rowg][colb + q*4 + 1];
        vq.z = Ts[rowg][colb + q*4 + 2];
        vq.w = Ts[rowg][colb + q*4 + 3];
        dst[q] = vq;
      }
    }
  }
}

// shared radix machinery: 10-bit levels, reduce over 4 buckets/thread
#define RADIX_REDUCE_AND_PICK(levelVar)                                           \
  int h0 = 0, h1 = 0, h2 = 0, h3 = 0;                                             \
  _Pragma("unroll")                                                               \
  for (int j = 0; j < NSUB; ++j) {                                                \
    int4 hq = *(int4*)&hist[j * HPITCH + 4 * t];                                  \
    h0 += hq.x; h1 += hq.y; h2 += hq.z; h3 += hq.w;                               \
  }                                                                               \
  int ht = h0 + h1 + h2 + h3;                                                     \
  int s = ht;                                                                     \
  _Pragma("unroll")                                                               \
  for (int off = 1; off < 64; off <<= 1) {                                        \
    int o = __shfl(s, lane + off);                                                \
    if (lane + off < 64) s += o;                                                  \
  }                                                                               \
  if (lane == 0) wtot[wv] = s;                                                    \
  __syncthreads();                                                                \
  int aw = 0;                                                                     \
  for (int w = wv + 1; w < 4; ++w) aw += wtot[w];                                 \
  int Sincl = s + aw;                                                             \
  int above3 = Sincl - ht;                                                        \
  int above2 = above3 + h3;                                                       \
  int above1 = above2 + h2;                                                       \
  int above0 = above1 + h1;                                                       \
  int hh[4] = {h0, h1, h2, h3};                                                   \
  int ab[4] = {above0, above1, above2, above3};                                   \
  _Pragma("unroll")                                                               \
  for (int q = 0; q < 4; ++q) {                                                   \
    if (ab[q] < R && R <= ab[q] + hh[q]) {                                        \
      unsigned v = (unsigned)(4 * t + q);                                         \
      int strictNow = sA + ab[q];                                                 \
      sT = T | (v << shift);                                                      \
      sM = M | (bmask << shift);                                                  \
      sA = strictNow;                                                             \
      sR = R - ab[q];                                                             \
      sDone = (strictNow + hh[q] <= NCAND) || ((levelVar) == 3);                  \
    }                                                                             \
  }                                                                               \
  __syncthreads();

// ---------------- radix-select from precomputed D (10-bit levels, keys in LDS) ----------------
__global__ __launch_bounds__(256) void select_k(const float* __restrict__ D,
                                                int* __restrict__ cand, int b, int n0) {
  __shared__ __align__(16) unsigned keys[NPTS];
  __shared__ __align__(16) int hist[HISTN];
  __shared__ int wtot[4];
  __shared__ unsigned sT;
  __shared__ unsigned sM;
  __shared__ int sR;
  __shared__ int sA;
  __shared__ int sDone;
  __shared__ int sCnt;
  int t = threadIdx.x;
  int wv = t >> 6;
  int lane = t & 63;
  int* hrow = hist + (t & (NSUB - 1)) * HPITCH;
  int r = blockIdx.x;
  const float4* drow4 = (const float4*)(D + (size_t)r * NPTS);
  int4 z4 = {0, 0, 0, 0};
  #pragma unroll
  for (int i = 0; i < (HISTN/4 + 255) / 256; ++i) {
    int idx = i * 256 + t;
    if (idx < HISTN/4) ((int4*)hist)[idx] = z4;
  }
  if (t == 0) { sT = 0u; sM = 0u; sR = RANKT; sA = 0; sDone = 0; sCnt = 0; }
  __syncthreads();
  // load keys + fused level-0 histogram (bits 22..31)
  #pragma unroll
  for (int i = 0; i < 4; ++i) {
    float4 d4 = drow4[i*256 + t];
    uint4 k4;
    k4.x = fkey(d4.x); k4.y = fkey(d4.y); k4.z = fkey(d4.z); k4.w = fkey(d4.w);
    ((uint4*)keys)[i*256 + t] = k4;
    atomicAdd(&hrow[k4.x >> 22], 1);
    atomicAdd(&hrow[k4.y >> 22], 1);
    atomicAdd(&hrow[k4.z >> 22], 1);
    atomicAdd(&hrow[k4.w >> 22], 1);
  }
  __syncthreads();
  int done = 0;
  for (int level = 0; level < 4 && !done; ++level) {
    unsigned M = sM, T = sT;
    int R = sR;
    int shift = (level < 3) ? (22 - 10 * level) : 0;
    unsigned bmask = (level < 3) ? 0x3ffu : 0x3u;
    if (level > 0) {
      #pragma unroll
      for (int i = 0; i < (HISTN/4 + 255) / 256; ++i) {
        int idx = i * 256 + t;
        if (idx < HISTN/4) ((int4*)hist)[idx] = z4;
      }
      __syncthreads();
      #pragma unroll
      for (int i = 0; i < 4; ++i) {
        uint4 k4 = ((uint4*)keys)[i*256 + t];
        if ((k4.x & M) == T) atomicAdd(&hrow[(k4.x >> shift) & bmask], 1);
        if ((k4.y & M) == T) atomicAdd(&hrow[(k4.y >> shift) & bmask], 1);
        if ((k4.z & M) == T) atomicAdd(&hrow[(k4.z >> shift) & bmask], 1);
        if ((k4.w & M) == T) atomicAdd(&hrow[(k4.w >> shift) & bmask], 1);
      }
      __syncthreads();
    }
    RADIX_REDUCE_AND_PICK(level)
    done = sDone;
  }
  unsigned T = sT;
  int* orow = cand + ((size_t)b * NPTS + n0 + r) * NCAND;
  #pragma unroll
  for (int i = 0; i < 4; ++i) {
    uint4 k4 = ((uint4*)keys)[i*256 + t];
    int mb = 4 * (i*256 + t);
    if (k4.x >= T) { int p = atomicAdd(&sCnt, 1); if (p < NCAND) orow[p] = mb + 0; }
    if (k4.y >= T) { int p = atomicAdd(&sCnt, 1); if (p < NCAND) orow[p] = mb + 1; }
    if (k4.z >= T) { int p = atomicAdd(&sCnt, 1); if (p < NCAND) orow[p] = mb + 2; }
    if (k4.w >= T) { int p = atomicAdd(&sCnt, 1); if (p < NCAND) orow[p] = mb + 3; }
  }
  __syncthreads();
  int c = sCnt; if (c > NCAND) c = NCAND;
  if (t >= c && t < NCAND) orow[t] = 0x7fffffff;
}

// ---------------- fused C=3 distance + radix-select (10-bit levels, recomputed keys) ----------------
__global__ __launch_bounds__(256) void select3_k(const float* __restrict__ X,
                                                 int* __restrict__ cand) {
  __shared__ __align__(16) int hist[HISTN];
  __shared__ int wtot[4];
  __shared__ unsigned sT;
  __shared__ unsigned sM;
  __shared__ int sR;
  __shared__ int sA;
  __shared__ int sDone;
  __shared__ int sCnt;
  int t = threadIdx.x;
  int wv = t >> 6;
  int lane = t & 63;
  int* hrow = hist + (t & (NSUB - 1)) * HPITCH;
  int r = blockIdx.x;
  int b = r >> 12, n = r & 4095;
  const float* xb = X + (size_t)b * NPTS * 3;
  float x0 = xb[n*3+0], x1 = xb[n*3+1], x2 = xb[n*3+2];
  int4 z4 = {0, 0, 0, 0};
  #pragma unroll
  for (int i = 0; i < (HISTN/4 + 255) / 256; ++i) {
    int idx = i * 256 + t;
    if (idx < HISTN/4) ((int4*)hist)[idx] = z4;
  }
  if (t == 0) { sT = 0u; sM = 0u; sR = RANKT; sA = 0; sDone = 0; sCnt = 0; }
  __syncthreads();
  #pragma unroll
  for (int i = 0; i < 16; ++i) {
    int m = i*256 + t;
    unsigned k = key3(x0, x1, x2, xb + m*3);
    atomicAdd(&hrow[k >> 22], 1);
  }
  __syncthreads();
  int done = 0;
  for (int level = 0; level < 4 && !done; ++level) {
    unsigned M = sM, T = sT;
    int R = sR;
    int shift = (level < 3) ? (22 - 10 * level) : 0;
    unsigned bmask = (level < 3) ? 0x3ffu : 0x3u;
    if (level > 0) {
      #pragma unroll
      for (int i = 0; i < (HISTN/4 + 255) / 256; ++i) {
        int idx = i * 256 + t;
        if (idx < HISTN/4) ((int4*)hist)[idx] = z4;
      }
      __syncthreads();
      #pragma unroll
      for (int i = 0; i < 16; ++i) {
        int m = i*256 + t;
        unsigned k = key3(x0, x1, x2, xb + m*3);
        if ((k & M) == T) atomicAdd(&hrow[(k >> shift) & bmask], 1);
      }
      __syncthreads();
    }
    RADIX_REDUCE_AND_PICK(level)
    done = sDone;
  }
  unsigned T = sT;
  int* orow = cand + (size_t)r * NCAND;
  #pragma unroll
  for (int i = 0; i < 16; ++i) {
    int m = i*256 + t;
    unsigned k = key3(x0, x1, x2, xb + m*3);
    if (k >= T) {
      int p = atomicAdd(&sCnt, 1);
      if (p < NCAND) orow[p] = m;
    }
  }
  __syncthreads();
  int c = sCnt; if (c > NCAND) c = NCAND;
  if (t >= c && t < NCAND) orow[t] = 0x7fffffff;
}

// ---------------- fp64 refinement: 64 lanes/row, ILP-4, 64-lane bitonic sort ----------------
__global__ __launch_bounds__(256) void refine_k(const float* __restrict__ X, int ldx, int C,
                                                const int* __restrict__ cand,
                                                int* __restrict__ idx) {
  int t = threadIdx.x;
  int lane = t & 63;
  int row = blockIdx.x * 4 + (t >> 6);
  int b = row >> 12, n = row & 4095;
  const float* Xb = X + (size_t)b * NPTS * ldx;
  const float* xn = Xb + (size_t)n * ldx;
  int m = cand[(size_t)row * NCAND + lane];
  double s;
  if (m >= NPTS) {
    s = 1e300;
  } else if (C == 3) {
    const float* xm = Xb + (size_t)m * 3;
    double d0 = (double)xn[0] - xm[0];
    double d1 = (double)xn[1] - xm[1];
    double d2 = (double)xn[2] - xm[2];
    s = d0*d0 + d1*d1 + d2*d2;
  } else {
    const float* xm = Xb + (size_t)m * ldx;
    double s0 = 0, s1 = 0, s2 = 0, s3 = 0;
    for (int c = 0; c < C; c += 4) {
      float4 a = *(const float4*)(xn + c);
      float4 q = *(const float4*)(xm + c);
      double e0 = (double)a.x - q.x; s0 += e0*e0;
      double e1 = (double)a.y - q.y; s1 += e1*e1;
      double e2 = (double)a.z - q.z; s2 += e2*e2;
      double e3 = (double)a.w - q.w; s3 += e3*e3;
    }
    s = (s0 + s1) + (s2 + s3);
  }
  #pragma unroll
  for (int k = 2; k <= 64; k <<= 1) {
    #pragma unroll
    for (int j = k >> 1; j > 0; j >>= 1) {
      double os = __shfl_xor(s, j);
      int om = __shfl_xor(m, j);
      bool up = ((lane & k) == 0);
      bool keepSmall = (((lane & j) == 0) == up);
      bool iGreater = (s > os) || (s == os && m > om);
      if (keepSmall == iGreater) { s = os; m = om; }
    }
  }
  if (lane < KNN) idx[(size_t)row * KNN + lane] = m;
}

// ---------------- 64-tile fp32 GEMM (small-O value path; unchanged k-order) ----------------
__global__ __launch_bounds__(256) void gemm_k(const float* __restrict__ X, int ldx,
                                              const float* __restrict__ W, int ldw,
                                              float* __restrict__ out, int ldo,
                                              const float* __restrict__ bias2d, int bstride,
                                              int C) {
  __shared__ float As[16][66];
  __shared__ float Bs[16][66];
  int t = threadIdx.x;
  int tx = t & 15, ty = t >> 4;
  int obase = blockIdx.x * 64;
  int rbase = blockIdx.y * 64;
  float acc[4][4] = {};
  int kk = t & 15, r0 = t >> 4;
  for (int kc = 0; kc < C; kc += 16) {
    #pragma unroll
    for (int i = 0; i < 4; ++i) {
      int rr = r0 + i * 16;
      float a = 0.f, bv = 0.f;
      if (kc + kk < C) {
        a  = X[(size_t)(rbase + rr) * ldx + kc + kk];
        bv = W[(size_t)(obase + rr) * ldw + kc + kk];
      }
      As[kk][rr] = a;
      Bs[kk][rr] = bv;
    }
    __syncthreads();
    #pragma unroll
    for (int k = 0; k < 16; ++k) {
      float av[4], bv2[4];
      #pragma unroll
      for (int i = 0; i < 4; ++i) { av[i] = As[k][ty + 16*i]; bv2[i] = Bs[k][tx + 16*i]; }
      #pragma unroll
      for (int i = 0; i < 4; ++i)
        #pragma unroll
        for (int j = 0; j < 4; ++j)
          acc[i][j] += av[i] * bv2[j];
    }
    __syncthreads();
  }
  #pragma unroll
  for (int i = 0; i < 4; ++i) {
    int r = rbase + ty + 16*i;
    #pragma unroll
    for (int j = 0; j < 4; ++j) {
      int o = obase + tx + 16*j;
      float val = acc[i][j];
      if (bias2d) val += bias2d[(r >> 12) * bstride + o];
      out[(size_t)r * ldo + o] = val;
    }
  }
}

// ---------------- split W -> Wn, Wd = Wc - Wn ----------------
__global__ __launch_bounds__(256) void prep_w(const float* __restrict__ W,
                                              float* __restrict__ wn, float* __restrict__ wd,
                                              int O, int C) {
  int i = blockIdx.x * 256 + threadIdx.x;
  if (i >= O * C) return;
  int o = i / C, c = i - o * C;
  float nn = W[(size_t)o * 2 * C + c];
  float cc = W[(size_t)o * 2 * C + C + c];
  wn[i] = nn;
  wd[i] = cc - nn;
}

// ---------------- single gather: per-(point,channel) max/min + fp64 stats ----------------
__global__ __launch_bounds__(256) void gather_k(const float* __restrict__ u, const float* __restrict__ v,
                                                const int* __restrict__ idx,
                                                float* __restrict__ mxb, float* __restrict__ mnb,
                                                double* __restrict__ gsum, double* __restrict__ gsq, int O) {
  __shared__ int sidx[16 * KNN];
  int t = threadIdx.x;
  int p0 = blockIdx.x * 16;
  int b = p0 >> 12;
  const int* ib = idx + (size_t)p0 * KNN;
  for (int i = t; i < 16 * KNN; i += 256) sidx[i] = ib[i];
  __syncthreads();
  int o = t & (O - 1);
  int pl = t / O;
  int ppi = 256 / O;
  const float* ub = u + ((size_t)b << 12) * O;
  double S = 0.0, S2 = 0.0;
  for (int p = pl; p < 16; p += ppi) {
    int r = p0 + p;
    float vv = v[(size_t)r * O + o];
    float mx = -3.4e38f, mn = 3.4e38f;
    double su = 0.0, su2 = 0.0;
    #pragma unroll
    for (int k = 0; k < KNN; ++k) {
      int m = sidx[p * KNN + k];
      float uv = ub[(size_t)m * O + o];
      mx = fmaxf(mx, uv);
      mn = fminf(mn, uv);
      double du = uv;
      su += du; su2 += du * du;
    }
    mxb[(size_t)r * O + o] = mx;
    mnb[(size_t)r * O + o] = mn;
    double dv = vv;
    S  += su + (double)KNN * dv;
    S2 += su2 + 2.0 * dv * su + (double)KNN * dv * dv;
  }
  atomicAdd(&gsum[o], S);
  atomicAdd(&gsq[o], S2);
}

// ---------------- finalize BN coeffs (fp64) ----------------
__global__ __launch_bounds__(256) void finalize_k(const double* __restrict__ gsum, const double* __restrict__ gsq,
                                                  const float* __restrict__ g, const float* __restrict__ bp,
                                                  float* __restrict__ a, float* __restrict__ bb,
                                                  double invM, int O) {
  int o = blockIdx.x * 256 + threadIdx.x;
  if (o >= O) return;
  double mean = gsum[o] * invM;
  double var = gsq[o] * invM - mean * mean;
  double sc = (double)g[o] / sqrt(var + 1e-5);
  a[o] = (float)sc;
  bb[o] = (float)((double)bp[o] - mean * sc);
}

// ---------------- edge output: elementwise from precomputed max/min ----------------
__global__ __launch_bounds__(256) void edge_out2(const float* __restrict__ v,
                                                 const float* __restrict__ mxb, const float* __restrict__ mnb,
                                                 const float* __restrict__ a, const float* __restrict__ bb,
                                                 float* __restrict__ xc, int coff, int O, int lgO) {
  int i = blockIdx.x * 256 + threadIdx.x;
  int r = i >> lgO, o = i & (O - 1);
  float av = a[o];
  float sel = av >= 0.f ? mxb[i] : mnb[i];
  float val = av * (v[i] + sel) + bb[o];
  xc[(size_t)r * 512 + coff + o] = lrelu(val);
}

// ---------------- per-column fp64 stats over rows ----------------
__global__ __launch_bounds__(256) void col_stats(const float* __restrict__ y, int ld, int O,
                                                 double* __restrict__ gsum, double* __restrict__ gsq) {
  int t = threadIdx.x;
  int r0 = blockIdx.x * 64;
  double s0 = 0, q0 = 0, s1 = 0, q1 = 0;
  for (int rr = 0; rr < 64; ++rr) {
    const float* row = y + (size_t)(r0 + rr) * ld;
    if (t < O) { double v0 = row[t]; s0 += v0; q0 += v0 * v0; }
    if (O == 512) { double v1 = row[t + 256]; s1 += v1; q1 += v1 * v1; }
  }
  if (t < O) { atomicAdd(&gsum[t], s0); atomicAdd(&gsq[t], q0); }
  if (O == 512) { atomicAdd(&gsum[t + 256], s1); atomicAdd(&gsq[t + 256], q1); }
}

// ---------------- conv5: BN+lrelu then global max over n ----------------
__global__ __launch_bounds__(256) void conv5_max(const float* __restrict__ y,
                                                 const float* __restrict__ a, const float* __restrict__ bb,
                                                 unsigned* __restrict__ gmax) {
  int t = threadIdx.x;
  int b = blockIdx.y;
  int r0 = (b << 12) + blockIdx.x * 64;
  float a0 = a[t], a1 = a[t + 256], b0 = bb[t], b1 = bb[t + 256];
  float m0 = -3.4e38f, m1 = -3.4e38f;
  for (int rr = 0; rr < 64; ++rr) {
    const float* row = y + (size_t)(r0 + rr) * 512;
    float v0 = lrelu(a0 * row[t] + b0);
    float v1 = lrelu(a1 * row[t + 256] + b1);
    m0 = fmaxf(m0, v0);
    m1 = fmaxf(m1, v1);
  }
  atomicMax(&gmax[b * 512 + t], fkey(m0));
  atomicMax(&gmax[b * 512 + t + 256], fkey(m1));
}

// ---------------- gterm[b,o] = sum_c gmax[b,c] * Ws1[o, 512+c] (fp64 acc) ----------------
__global__ __launch_bounds__(256) void gterm_k(const unsigned* __restrict__ gmax,
                                               const float* __restrict__ Ws1,
                                               float* __restrict__ gt) {
  int b = blockIdx.x, o = threadIdx.x;
  double acc = 0.0;
  for (int c = 0; c < 512; ++c)
    acc += (double)funkey(gmax[b * 512 + c]) * (double)Ws1[(size_t)o * 1024 + 512 + c];
  gt[b * 256 + o] = (float)acc;
}

// ---------------- elementwise BN + lrelu ----------------
__global__ __launch_bounds__(256) void bn_apply(const float* __restrict__ y, int ld,
                                                const float* __restrict__ a, const float* __restrict__ bb,
                                                float* __restrict__ out, int ldo, int O) {
  int t = threadIdx.x;
  int o = t & (O - 1);
  int pl = t / O;
  int rpi = 256 / O;
  int r0 = blockIdx.x * 64;
  float av = a[o], bv = bb[o];
  for (int rr = pl; rr < 64; rr += rpi) {
    int r = r0 + rr;
    float val = av * y[(size_t)r * ld + o] + bv;
    out[(size_t)r * ldo + o] = lrelu(val);
  }
}

// ---------------- final 2-channel projection (fp64 acc), output (B,2,N) ----------------
__global__ __launch_bounds__(256) void final_out(const float* __restrict__ h,
                                                 const float* __restrict__ Ws3,
                                                 const float* __restrict__ bias3,
                                                 float* __restrict__ out) {
  int rr = blockIdx.x * 256 + threadIdx.x;
  if (rr >= MROWS) return;
  int b = rr >> 12, n = rr & 4095;
  const float* row = h + (size_t)rr * 128;
  double a0 = 0.0, a1 = 0.0;
  for (int c = 0; c < 128; ++c) {
    double hv = row[c];
    a0 += hv * (double)Ws3[c];
    a1 += hv * (double)Ws3[128 + c];
  }
  out[((size_t)b * 2) * NPTS + n] = (float)(a0 + (double)bias3[0]);
  out[((size_t)b * 2 + 1) * NPTS + n] = (float)(a1 + (double)bias3[1]);
}

extern "C" void kernel_launch(void* const* d_in, const int* in_sizes, int n_in,
                              void* d_out, int out_size, void* d_ws, size_t ws_size,
                              hipStream_t stream) {
  const float* points = (const float*)d_in[0];
  const float* W1 = (const float*)d_in[1];  const float* g1 = (const float*)d_in[2];  const float* b1 = (const float*)d_in[3];
  const float* W2 = (const float*)d_in[4];  const float* g2 = (const float*)d_in[5];  const float* b2 = (const float*)d_in[6];
  const float* W3 = (const float*)d_in[7];  const float* g3 = (const float*)d_in[8];  const float* b3 = (const float*)d_in[9];
  const float* W4 = (const float*)d_in[10]; const float* g4 = (const float*)d_in[11]; const float* b4 = (const float*)d_in[12];
  const float* W5 = (const float*)d_in[13]; const float* g5 = (const float*)d_in[14]; const float* b5 = (const float*)d_in[15];
  const float* Ws1 = (const float*)d_in[16]; const float* gs1 = (const float*)d_in[17]; const float* bs1 = (const float*)d_in[18];
  const float* Ws2 = (const float*)d_in[19]; const float* gs2 = (const float*)d_in[20]; const float* bs2 = (const float*)d_in[21];
  const float* Ws3 = (const float*)d_in[22]; const float* bias3 = (const float*)d_in[23];

  size_t fixedBytes = (size_t)(MROWS*NCAND*4) + (size_t)(MROWS*KNN*4) + (size_t)(MROWS*4)
                    + 2*(size_t)MROWS*256*4 + (size_t)MROWS*512*4 + 2*(256*128*4)
                    + 8*1024 + 4*1024 + NB*512*4 + NB*256*4 + 64*1024;
  int CH = (ws_size >= (size_t)4096 * NPTS * 4 + fixedBytes) ? 4096 : 2048;

  char* p = (char*)d_ws;
  auto carve = [&](size_t nbytes) -> char* {
    char* q = p;
    p += (nbytes + 255) & ~(size_t)255;
    return q;
  };
  float* big  = (float*)carve((size_t)CH * NPTS * 4);   // D batch / conv5 y / mx+mn
  int*   candb = (int*)carve((size_t)MROWS * NCAND * 4);
  int*   idxb = (int*)carve((size_t)MROWS * KNN * 4);
  float* xx   = (float*)carve((size_t)MROWS * 4);
  float* u    = (float*)carve((size_t)MROWS * 256 * 4);
  float* v    = (float*)carve((size_t)MROWS * 256 * 4);
  float* xcb  = (float*)carve((size_t)MROWS * 512 * 4);
  float* wn   = (float*)carve(256 * 128 * 4);
  float* wd   = (float*)carve(256 * 128 * 4);
  double* gsum = (double*)carve(512 * 8);
  double* gsq  = (double*)carve(512 * 8);
  float* acoef = (float*)carve(512 * 4);
  float* bcoef = (float*)carve(512 * 4);
  unsigned* gmax = (unsigned*)carve(NB * 512 * 4);
  float* gtermb = (float*)carve(NB * 256 * 4);
  float* h1n = u;
  float* h2n = v;

  auto edge = [&](const float* X, int ldx, int C, int O, int lgO,
                  const float* W, const float* g, const float* bp, int coff) {
    if (C == 3) {
      select3_k<<<MROWS, 256, 0, stream>>>(X, candb);
    } else {
      sqnorm_k<<<MROWS / 256, 256, 0, stream>>>(X, ldx, C, xx);
      if (CH == 4096) {
        for (int b = 0; b < NB; ++b) {
          dist_tri_k<<<528, 256, 0, stream>>>(X + (size_t)b * NPTS * ldx, ldx, C,
                                              xx + b * NPTS, big);
          select_k<<<NPTS, 256, 0, stream>>>(big, candb, b, 0);
        }
      } else {
        for (int b = 0; b < NB; ++b) {
          for (int n0 = 0; n0 < NPTS; n0 += CH) {
            gemm128_k<<<dim3(NPTS / 128, CH / 128), 256, 0, stream>>>(
                X + ((size_t)b * NPTS + n0) * ldx, ldx,
                X + (size_t)b * NPTS * ldx, ldx, C,
                big, NPTS, nullptr, 0,
                xx + b * NPTS + n0, xx + b * NPTS);
            select_k<<<CH, 256, 0, stream>>>(big, candb, b, n0);
          }
        }
      }
    }
    refine_k<<<MROWS / 4, 256, 0, stream>>>(X, ldx, C, candb, idxb);
    prep_w<<<(O * C + 255) / 256, 256, 0, stream>>>(W, wn, wd, O, C);
    if (O >= 256) {
      gemm128_k<<<dim3(O / 128, MROWS / 128), 256, 0, stream>>>(X, ldx, wn, C, C, u, O, nullptr, 0, nullptr, nullptr);
      gemm128_k<<<dim3(O / 128, MROWS / 128), 256, 0, stream>>>(X, ldx, wd, C, C, v, O, nullptr, 0, nullptr, nullptr);
    } else {
      gemm_k<<<dim3(O / 64, MROWS / 64), 256, 0, stream>>>(X, ldx, wn, C, u, O, nullptr, 0, C);
      gemm_k<<<dim3(O / 64, MROWS / 64), 256, 0, stream>>>(X, ldx, wd, C, v, O, nullptr, 0, C);
    }
    hipMemsetAsync(gsum, 0, 512 * 8 * 2, stream);
    float* mxb = big;
    float* mnb = big + (size_t)MROWS * O;
    gather_k<<<MROWS / 16, 256, 0, stream>>>(u, v, idxb, mxb, mnb, gsum, gsq, O);
    finalize_k<<<(O + 255) / 256, 256, 0, stream>>>(gsum, gsq, g, bp, acoef, bcoef,
                                                    1.0 / ((double)MROWS * KNN), O);
    edge_out2<<<(MROWS * O) / 256, 256, 0, stream>>>(v, mxb, mnb, acoef, bcoef, xcb, coff, O, lgO);
  };

  edge(points,    3,   3,  64, 6, W1, g1, b1, 0);
  edge(xcb,       512, 64, 64, 6, W2, g2, b2, 64);
  edge(xcb + 64,  512, 64, 128, 7, W3, g3, b3, 128);
  edge(xcb + 128, 512, 128, 256, 8, W4, g4, b4, 256);

  // conv5: y5 = xc @ W5^T  (B,N,512)
  gemm128_k<<<dim3(4, MROWS / 128), 256, 0, stream>>>(xcb, 512, W5, 512, 512, big, 512, nullptr, 0, nullptr, nullptr);
  hipMemsetAsync(gsum, 0, 512 * 8 * 2, stream);
  col_stats<<<MROWS / 64, 256, 0, stream>>>(big, 512, 512, gsum, gsq);
  finalize_k<<<2, 256, 0, stream>>>(gsum, gsq, g5, b5, acoef, bcoef, 1.0 / MROWS, 512);
  hipMemsetAsync(gmax, 0, NB * 512 * 4, stream);
  conv5_max<<<dim3(NPTS / 64, NB), 256, 0, stream>>>(big, acoef, bcoef, gmax);
  gterm_k<<<NB, 256, 0, stream>>>(gmax, Ws1, gtermb);

  // h1 = lrelu(bn(xc @ Ws1a^T + gterm))
  gemm128_k<<<dim3(2, MROWS / 128), 256, 0, stream>>>(xcb, 512, Ws1, 1024, 512, big, 256, gtermb, 256, nullptr, nullptr);
  hipMemsetAsync(gsum, 0, 512 * 8 * 2, stream);
  col_stats<<<MROWS / 64, 256, 0, stream>>>(big, 256, 256, gsum, gsq);
  finalize_k<<<1, 256, 0, stream>>>(gsum, gsq, gs1, bs1, acoef, bcoef, 1.0 / MROWS, 256);
  bn_apply<<<MROWS / 64, 256, 0, stream>>>(big, 256, acoef, bcoef, h1n, 256, 256);

  // h2 = lrelu(bn(h1 @ Ws2^T))
  gemm_k<<<dim3(2, MROWS / 64), 256, 0, stream>>>(h1n, 256, Ws2, 256, big, 128, nullptr, 0, 256);
  hipMemsetAsync(gsum, 0, 512 * 8 * 2, stream);
  col_stats<<<MROWS / 64, 256, 0, stream>>>(big, 128, 128, gsum, gsq);
  finalize_k<<<1, 256, 0, stream>>>(gsum, gsq, gs2, bs2, acoef, bcoef, 1.0 / MROWS, 128);
  bn_apply<<<MROWS / 64, 256, 0, stream>>>(big, 128, acoef, bcoef, h2n, 128, 128);

  // out = h2 @ Ws3^T + bias3 -> (B,2,N)
  final_out<<<MROWS / 256, 256, 0, stream>>>(h2n, Ws3, bias3, (float*)d_out);
}

// Round 12
// 2016.309 us; speedup vs baseline: 1.0709x; 1.0709x over previous
//
#include <hip/hip_runtime.h>

#define NPTS 4096
#define NB 4
#define KNN 20
#define NCAND 64
#define RANKT 32
#define MROWS (NB*NPTS)
#define HISTN (16*257)

__device__ __forceinline__ float lrelu(float v) { return v >= 0.f ? v : 0.2f * v; }

__device__ __forceinline__ unsigned fkey(float f) {
  unsigned u = __float_as_uint(f);
  return (u & 0x80000000u) ? ~u : (u | 0x80000000u);
}
__device__ __forceinline__ float funkey(unsigned k) {
  unsigned u = (k & 0x80000000u) ? (k ^ 0x80000000u) : ~k;
  return __uint_as_float(u);
}

// ---------------- squared norms (fp32) ----------------
__global__ __launch_bounds__(256) void sqnorm_k(const float* __restrict__ X, int ldx, int C,
                                                float* __restrict__ xx) {
  int r = blockIdx.x * 256 + threadIdx.x;
  if (r >= MROWS) return;
  const float* row = X + (size_t)r * ldx;
  float s = 0.f;
  for (int c = 0; c < C; ++c) { float v = row[c]; s += v * v; }
  xx[r] = s;
}

// ---------------- unified 128x128 fp32 GEMM ----------------
// value mode (xxa==null): out[r,m] = sum_c A[r,c]*B[m,c] (+bias2d); optional fused col stats
// dist  mode (xxa!=null): out[r,m] = 2*acc - xxa[r] - xxb[m]
__global__ __launch_bounds__(256, 2) void gemm128_k(
    const float* __restrict__ A, int lda,
    const float* __restrict__ B, int ldb, int C,
    float* __restrict__ out, int ldo,
    const float* __restrict__ bias2d, int bstride,
    const float* __restrict__ xxa, const float* __restrict__ xxb,
    double* __restrict__ colsum, double* __restrict__ colsq) {
  __shared__ float As[32][128];
  __shared__ float Bs[32][128];
  int t = threadIdx.x;
  int tx = t & 15, ty = t >> 4;
  int mbase = blockIdx.x * 128;
  int rbase = blockIdx.y * 128;
  float acc[8][8] = {};
  int lr = t >> 1;
  int lk = (t & 1) * 16;
  const float* pa0 = A + (size_t)(rbase + lr) * lda + lk;
  const float* pb0 = B + (size_t)(mbase + lr) * ldb + lk;
  for (int kc = 0; kc < C; kc += 32) {
    const float* pa = pa0 + kc;
    const float* pb = pb0 + kc;
    #pragma unroll
    for (int j4 = 0; j4 < 4; ++j4) {
      float4 a4 = *(const float4*)(pa + j4 * 4);
      float4 b4 = *(const float4*)(pb + j4 * 4);
      As[lk + j4*4 + 0][lr] = a4.x;
      As[lk + j4*4 + 1][lr] = a4.y;
      As[lk + j4*4 + 2][lr] = a4.z;
      As[lk + j4*4 + 3][lr] = a4.w;
      Bs[lk + j4*4 + 0][lr] = b4.x;
      Bs[lk + j4*4 + 1][lr] = b4.y;
      Bs[lk + j4*4 + 2][lr] = b4.z;
      Bs[lk + j4*4 + 3][lr] = b4.w;
    }
    __syncthreads();
    #pragma unroll
    for (int k = 0; k < 32; ++k) {
      float4 a0 = ((const float4*)As[k])[ty];
      float4 a1 = ((const float4*)As[k])[16 + ty];
      float4 b0 = ((const float4*)Bs[k])[tx];
      float4 b1 = ((const float4*)Bs[k])[16 + tx];
      float av[8] = {a0.x,a0.y,a0.z,a0.w,a1.x,a1.y,a1.z,a1.w};
      float bv[8] = {b0.x,b0.y,b0.z,b0.w,b1.x,b1.y,b1.z,b1.w};
      #pragma unroll
      for (int i = 0; i < 8; ++i)
        #pragma unroll
        for (int j = 0; j < 8; ++j)
          acc[i][j] += av[i] * bv[j];
    }
    __syncthreads();
  }
  float psum[8] = {};
  float psq[8] = {};
  #pragma unroll
  for (int ih = 0; ih < 2; ++ih) {
    #pragma unroll
    for (int i4 = 0; i4 < 4; ++i4) {
      int i = ih * 4 + i4;
      int r = rbase + ih * 64 + ty * 4 + i4;
      float xr = xxa ? xxa[r] : 0.f;
      const float* brow = bias2d ? (bias2d + (size_t)(r >> 12) * bstride) : nullptr;
      #pragma unroll
      for (int jh = 0; jh < 2; ++jh) {
        float4 o4;
        #pragma unroll
        for (int j4 = 0; j4 < 4; ++j4) {
          int j = jh * 4 + j4;
          int m = mbase + jh * 64 + tx * 4 + j4;
          float val = acc[i][j];
          if (xxa) val = 2.f * val - xr - xxb[m];
          else if (brow) val += brow[m];
          if (colsum) { psum[j] += val; psq[j] += val * val; }
          (&o4.x)[j4] = val;
        }
        *(float4*)&out[(size_t)r * ldo + mbase + jh * 64 + tx * 4] = o4;
      }
    }
  }
  if (colsum) {
    float* ls = (float*)As;
    float* lq = (float*)Bs;
    if (t < 128) { ls[t] = 0.f; lq[t] = 0.f; }
    __syncthreads();
    #pragma unroll
    for (int j = 0; j < 8; ++j) {
      int cl = (j >> 2) * 64 + tx * 4 + (j & 3);
      atomicAdd(&ls[cl], psum[j]);
      atomicAdd(&lq[cl], psq[j]);
    }
    __syncthreads();
    if (t < 128) {
      atomicAdd(&colsum[mbase + t], (double)ls[t]);
      atomicAdd(&colsq[mbase + t], (double)lq[t]);
    }
  }
}

// ---------------- symmetric-triangle distance GEMM (full batch, mirrored writes) ----------------
__global__ __launch_bounds__(256, 2) void dist_tri_k(const float* __restrict__ Xb, int ldx, int C,
                                                     const float* __restrict__ xxb,
                                                     float* __restrict__ D) {
  __shared__ float As[32][128];
  __shared__ float Bs[32][128];
  __shared__ float Ts[32][129];
  int t = threadIdx.x;
  int tx = t & 15, ty = t >> 4;
  int lin = blockIdx.x, bi = 0;
  while (lin >= 32 - bi) { lin -= 32 - bi; ++bi; }
  int bj = bi + lin;
  int rbase = bi * 128;
  int mbase = bj * 128;
  float acc[8][8] = {};
  int lr = t >> 1;
  int lk = (t & 1) * 16;
  const float* pa0 = Xb + (size_t)(rbase + lr) * ldx + lk;
  const float* pb0 = Xb + (size_t)(mbase + lr) * ldx + lk;
  for (int kc = 0; kc < C; kc += 32) {
    const float* pa = pa0 + kc;
    const float* pb = pb0 + kc;
    #pragma unroll
    for (int j4 = 0; j4 < 4; ++j4) {
      float4 a4 = *(const float4*)(pa + j4 * 4);
      float4 b4 = *(const float4*)(pb + j4 * 4);
      As[lk + j4*4 + 0][lr] = a4.x;
      As[lk + j4*4 + 1][lr] = a4.y;
      As[lk + j4*4 + 2][lr] = a4.z;
      As[lk + j4*4 + 3][lr] = a4.w;
      Bs[lk + j4*4 + 0][lr] = b4.x;
      Bs[lk + j4*4 + 1][lr] = b4.y;
      Bs[lk + j4*4 + 2][lr] = b4.z;
      Bs[lk + j4*4 + 3][lr] = b4.w;
    }
    __syncthreads();
    #pragma unroll
    for (int k = 0; k < 32; ++k) {
      float4 a0 = ((const float4*)As[k])[ty];
      float4 a1 = ((const float4*)As[k])[16 + ty];
      float4 b0 = ((const float4*)Bs[k])[tx];
      float4 b1 = ((const float4*)Bs[k])[16 + tx];
      float av[8] = {a0.x,a0.y,a0.z,a0.w,a1.x,a1.y,a1.z,a1.w};
      float bv[8] = {b0.x,b0.y,b0.z,b0.w,b1.x,b1.y,b1.z,b1.w};
      #pragma unroll
      for (int i = 0; i < 8; ++i)
        #pragma unroll
        for (int j = 0; j < 8; ++j)
          acc[i][j] += av[i] * bv[j];
    }
    __syncthreads();
  }
  #pragma unroll
  for (int ih = 0; ih < 2; ++ih) {
    #pragma unroll
    for (int i4 = 0; i4 < 4; ++i4) {
      int i = ih * 4 + i4;
      int r = rbase + ih * 64 + ty * 4 + i4;
      float xr = xxb[r];
      #pragma unroll
      for (int jh = 0; jh < 2; ++jh) {
        float4 o4;
        #pragma unroll
        for (int j4 = 0; j4 < 4; ++j4) {
          int j = jh * 4 + j4;
          int m = mbase + jh * 64 + tx * 4 + j4;
          float val = 2.f * acc[i][j] - xr - xxb[m];
          acc[i][j] = val;
          (&o4.x)[j4] = val;
        }
        *(float4*)&D[(size_t)r * NPTS + mbase + jh * 64 + tx * 4] = o4;
      }
    }
  }
  if (bi != bj) {
    #pragma unroll
    for (int g = 0; g < 4; ++g) {
      __syncthreads();
      #pragma unroll
      for (int jh = 0; jh < 2; ++jh) {
        int mlo = jh * 64 + tx * 4;
        if ((mlo >> 5) == g) {
          #pragma unroll
          for (int i = 0; i < 8; ++i) {
            int r_local = (i >> 2) * 64 + ty * 4 + (i & 3);
            #pragma unroll
            for (int j4 = 0; j4 < 4; ++j4)
              Ts[(mlo & 31) + j4][r_local] = acc[i][jh * 4 + j4];
          }
        }
      }
      __syncthreads();
      int rowg = t >> 3;
      int colb = (t & 7) * 16;
      int mg = mbase + g * 32 + rowg;
      float4* dst = (float4*)&D[(size_t)mg * NPTS + rbase + colb];
      #pragma unroll
      for (int q = 0; q < 4; ++q) {
        float4 vq;
        vq.x = Ts[rowg][colb + q*4 + 0];
        vq.y = Ts[rowg][colb + q*4 + 1];
        vq.z = Ts[rowg][colb + q*4 + 2];
        vq.w = Ts[rowg][colb + q*4 + 3];
        dst[q] = vq;
      }
    }
  }
}

// ---------------- radix-select from precomputed D (round-10 proven config) ----------------
__global__ __launch_bounds__(256) void select_k(const float* __restrict__ D,
                                                int* __restrict__ cand, int b, int n0) {
  __shared__ __align__(16) unsigned keys[NPTS];
  __shared__ __align__(16) int hist[HISTN];
  __shared__ int wtot[4];
  __shared__ unsigned sT;
  __shared__ unsigned sM;
  __shared__ int sR;
  __shared__ int sA;
  __shared__ int sDone;
  __shared__ int sCnt;
  int t = threadIdx.x;
  int wv = t >> 6;
  int lane = t & 63;
  int* hrow = hist + (t & 15) * 257;
  int r = blockIdx.x;
  const float4* drow4 = (const float4*)(D + (size_t)r * NPTS);
  int4 z4 = {0, 0, 0, 0};
  #pragma unroll
  for (int i = 0; i < HISTN/4/256 + 1; ++i) {
    int idx = i * 256 + t;
    if (idx < HISTN/4) ((int4*)hist)[idx] = z4;
  }
  if (t == 0) { sT = 0u; sM = 0u; sR = RANKT; sA = 0; sDone = 0; sCnt = 0; }
  __syncthreads();
  #pragma unroll
  for (int i = 0; i < 4; ++i) {
    float4 d4 = drow4[i*256 + t];
    uint4 k4;
    k4.x = fkey(d4.x); k4.y = fkey(d4.y); k4.z = fkey(d4.z); k4.w = fkey(d4.w);
    ((uint4*)keys)[i*256 + t] = k4;
    atomicAdd(&hrow[k4.x >> 24], 1);
    atomicAdd(&hrow[k4.y >> 24], 1);
    atomicAdd(&hrow[k4.z >> 24], 1);
    atomicAdd(&hrow[k4.w >> 24], 1);
  }
  __syncthreads();
  int done = 0;
  for (int level = 0; level < 4 && !done; ++level) {
    unsigned M = sM, T = sT;
    int R = sR;
    int shift = 24 - 8 * level;
    if (level > 0) {
      #pragma unroll
      for (int i = 0; i < HISTN/4/256 + 1; ++i) {
        int idx = i * 256 + t;
        if (idx < HISTN/4) ((int4*)hist)[idx] = z4;
      }
      __syncthreads();
      #pragma unroll
      for (int i = 0; i < 4; ++i) {
        uint4 k4 = ((uint4*)keys)[i*256 + t];
        if ((k4.x & M) == T) atomicAdd(&hrow[(k4.x >> shift) & 0xffu], 1);
        if ((k4.y & M) == T) atomicAdd(&hrow[(k4.y >> shift) & 0xffu], 1);
        if ((k4.z & M) == T) atomicAdd(&hrow[(k4.z >> shift) & 0xffu], 1);
        if ((k4.w & M) == T) atomicAdd(&hrow[(k4.w >> shift) & 0xffu], 1);
      }
      __syncthreads();
    }
    int h = 0;
    #pragma unroll
    for (int j = 0; j < 16; ++j) h += hist[j * 257 + t];
    int s = h;
    #pragma unroll
    for (int off = 1; off < 64; off <<= 1) {
      int o = __shfl(s, lane + off);
      if (lane + off < 64) s += o;
    }
    if (lane == 0) wtot[wv] = s;
    __syncthreads();
    int aw = 0;
    for (int w = wv + 1; w < 4; ++w) aw += wtot[w];
    int sAbove = (s - h) + aw;
    if (sAbove < R && R <= sAbove + h) {
      unsigned v = (unsigned)t;
      int strictNow = sA + sAbove;
      sT = T | (v << shift);
      sM = M | (0xffu << shift);
      sA = strictNow;
      sR = R - sAbove;
      sDone = (strictNow + h <= NCAND) || (level == 3);
    }
    __syncthreads();
    done = sDone;
  }
  unsigned T = sT;
  int* orow = cand + ((size_t)b * NPTS + n0 + r) * NCAND;
  #pragma unroll
  for (int i = 0; i < 4; ++i) {
    uint4 k4 = ((uint4*)keys)[i*256 + t];
    int mb = 4 * (i*256 + t);
    if (k4.x >= T) { int p = atomicAdd(&sCnt, 1); if (p < NCAND) orow[p] = mb + 0; }
    if (k4.y >= T) { int p = atomicAdd(&sCnt, 1); if (p < NCAND) orow[p] = mb + 1; }
    if (k4.z >= T) { int p = atomicAdd(&sCnt, 1); if (p < NCAND) orow[p] = mb + 2; }
    if (k4.w >= T) { int p = atomicAdd(&sCnt, 1); if (p < NCAND) orow[p] = mb + 3; }
  }
  __syncthreads();
  int c = sCnt; if (c > NCAND) c = NCAND;
  if (t >= c && t < NCAND) orow[t] = 0x7fffffff;
}

// ---------------- fused C=3 distance + radix-select (round-10 proven config) ----------------
__global__ __launch_bounds__(256) void select3_k(const float* __restrict__ X,
                                                 int* __restrict__ cand) {
  __shared__ __align__(16) unsigned keys[NPTS];
  __shared__ __align__(16) int hist[HISTN];
  __shared__ int wtot[4];
  __shared__ unsigned sT;
  __shared__ unsigned sM;
  __shared__ int sR;
  __shared__ int sA;
  __shared__ int sDone;
  __shared__ int sCnt;
  int t = threadIdx.x;
  int wv = t >> 6;
  int lane = t & 63;
  int* hrow = hist + (t & 15) * 257;
  int r = blockIdx.x;
  int b = r >> 12, n = r & 4095;
  const float* xb = X + (size_t)b * NPTS * 3;
  float x0 = xb[n*3+0], x1 = xb[n*3+1], x2 = xb[n*3+2];
  int4 z4 = {0, 0, 0, 0};
  #pragma unroll
  for (int i = 0; i < HISTN/4/256 + 1; ++i) {
    int idx = i * 256 + t;
    if (idx < HISTN/4) ((int4*)hist)[idx] = z4;
  }
  if (t == 0) { sT = 0u; sM = 0u; sR = RANKT; sA = 0; sDone = 0; sCnt = 0; }
  __syncthreads();
  #pragma unroll
  for (int i = 0; i < NPTS/256; ++i) {
    int m = i*256 + t;
    float d0 = x0 - xb[m*3+0];
    float d1 = x1 - xb[m*3+1];
    float d2 = x2 - xb[m*3+2];
    unsigned k = fkey(-(d0*d0 + d1*d1 + d2*d2));
    keys[m] = k;
    atomicAdd(&hrow[k >> 24], 1);
  }
  __syncthreads();
  int done = 0;
  for (int level = 0; level < 4 && !done; ++level) {
    unsigned M = sM, T = sT;
    int R = sR;
    int shift = 24 - 8 * level;
    if (level > 0) {
      #pragma unroll
      for (int i = 0; i < HISTN/4/256 + 1; ++i) {
        int idx = i * 256 + t;
        if (idx < HISTN/4) ((int4*)hist)[idx] = z4;
      }
      __syncthreads();
      #pragma unroll
      for (int i = 0; i < 4; ++i) {
        uint4 k4 = ((uint4*)keys)[i*256 + t];
        if ((k4.x & M) == T) atomicAdd(&hrow[(k4.x >> shift) & 0xffu], 1);
        if ((k4.y & M) == T) atomicAdd(&hrow[(k4.y >> shift) & 0xffu], 1);
        if ((k4.z & M) == T) atomicAdd(&hrow[(k4.z >> shift) & 0xffu], 1);
        if ((k4.w & M) == T) atomicAdd(&hrow[(k4.w >> shift) & 0xffu], 1);
      }
      __syncthreads();
    }
    int h = 0;
    #pragma unroll
    for (int j = 0; j < 16; ++j) h += hist[j * 257 + t];
    int s = h;
    #pragma unroll
    for (int off = 1; off < 64; off <<= 1) {
      int o = __shfl(s, lane + off);
      if (lane + off < 64) s += o;
    }
    if (lane == 0) wtot[wv] = s;
    __syncthreads();
    int aw = 0;
    for (int w = wv + 1; w < 4; ++w) aw += wtot[w];
    int sAbove = (s - h) + aw;
    if (sAbove < R && R <= sAbove + h) {
      unsigned v = (unsigned)t;
      int strictNow = sA + sAbove;
      sT = T | (v << shift);
      sM = M | (0xffu << shift);
      sA = strictNow;
      sR = R - sAbove;
      sDone = (strictNow + h <= NCAND) || (level == 3);
    }
    __syncthreads();
    done = sDone;
  }
  unsigned T = sT;
  int* orow = cand + (size_t)r * NCAND;
  #pragma unroll
  for (int i = 0; i < 4; ++i) {
    uint4 k4 = ((uint4*)keys)[i*256 + t];
    int mb = 4 * (i*256 + t);
    if (k4.x >= T) { int p = atomicAdd(&sCnt, 1); if (p < NCAND) orow[p] = mb + 0; }
    if (k4.y >= T) { int p = atomicAdd(&sCnt, 1); if (p < NCAND) orow[p] = mb + 1; }
    if (k4.z >= T) { int p = atomicAdd(&sCnt, 1); if (p < NCAND) orow[p] = mb + 2; }
    if (k4.w >= T) { int p = atomicAdd(&sCnt, 1); if (p < NCAND) orow[p] = mb + 3; }
  }
  __syncthreads();
  int c = sCnt; if (c > NCAND) c = NCAND;
  if (t >= c && t < NCAND) orow[t] = 0x7fffffff;
}

// ---------------- fp64 refinement: 64 lanes/row, ILP-4, 64-lane bitonic sort ----------------
__global__ __launch_bounds__(256) void refine_k(const float* __restrict__ X, int ldx, int C,
                                                const int* __restrict__ cand,
                                                int* __restrict__ idx) {
  int t = threadIdx.x;
  int lane = t & 63;
  int row = blockIdx.x * 4 + (t >> 6);
  int b = row >> 12, n = row & 4095;
  const float* Xb = X + (size_t)b * NPTS * ldx;
  const float* xn = Xb + (size_t)n * ldx;
  int m = cand[(size_t)row * NCAND + lane];
  double s;
  if (m >= NPTS) {
    s = 1e300;
  } else if (C == 3) {
    const float* xm = Xb + (size_t)m * 3;
    double d0 = (double)xn[0] - xm[0];
    double d1 = (double)xn[1] - xm[1];
    double d2 = (double)xn[2] - xm[2];
    s = d0*d0 + d1*d1 + d2*d2;
  } else {
    const float* xm = Xb + (size_t)m * ldx;
    double s0 = 0, s1 = 0, s2 = 0, s3 = 0;
    for (int c = 0; c < C; c += 4) {
      float4 a = *(const float4*)(xn + c);
      float4 q = *(const float4*)(xm + c);
      double e0 = (double)a.x - q.x; s0 += e0*e0;
      double e1 = (double)a.y - q.y; s1 += e1*e1;
      double e2 = (double)a.z - q.z; s2 += e2*e2;
      double e3 = (double)a.w - q.w; s3 += e3*e3;
    }
    s = (s0 + s1) + (s2 + s3);
  }
  #pragma unroll
  for (int k = 2; k <= 64; k <<= 1) {
    #pragma unroll
    for (int j = k >> 1; j > 0; j >>= 1) {
      double os = __shfl_xor(s, j);
      int om = __shfl_xor(m, j);
      bool up = ((lane & k) == 0);
      bool keepSmall = (((lane & j) == 0) == up);
      bool iGreater = (s > os) || (s == os && m > om);
      if (keepSmall == iGreater) { s = os; m = om; }
    }
  }
  if (lane < KNN) idx[(size_t)row * KNN + lane] = m;
}

// ---------------- 64-tile fp32 GEMM (C=3 value path; unchanged k-order) ----------------
__global__ __launch_bounds__(256) void gemm_k(const float* __restrict__ X, int ldx,
                                              const float* __restrict__ W, int ldw,
                                              float* __restrict__ out, int ldo,
                                              const float* __restrict__ bias2d, int bstride,
                                              int C) {
  __shared__ float As[16][66];
  __shared__ float Bs[16][66];
  int t = threadIdx.x;
  int tx = t & 15, ty = t >> 4;
  int obase = blockIdx.x * 64;
  int rbase = blockIdx.y * 64;
  float acc[4][4] = {};
  int kk = t & 15, r0 = t >> 4;
  for (int kc = 0; kc < C; kc += 16) {
    #pragma unroll
    for (int i = 0; i < 4; ++i) {
      int rr = r0 + i * 16;
      float a = 0.f, bv = 0.f;
      if (kc + kk < C) {
        a  = X[(size_t)(rbase + rr) * ldx + kc + kk];
        bv = W[(size_t)(obase + rr) * ldw + kc + kk];
      }
      As[kk][rr] = a;
      Bs[kk][rr] = bv;
    }
    __syncthreads();
    #pragma unroll
    for (int k = 0; k < 16; ++k) {
      float av[4], bv2[4];
      #pragma unroll
      for (int i = 0; i < 4; ++i) { av[i] = As[k][ty + 16*i]; bv2[i] = Bs[k][tx + 16*i]; }
      #pragma unroll
      for (int i = 0; i < 4; ++i)
        #pragma unroll
        for (int j = 0; j < 4; ++j)
          acc[i][j] += av[i] * bv2[j];
    }
    __syncthreads();
  }
  #pragma unroll
  for (int i = 0; i < 4; ++i) {
    int r = rbase + ty + 16*i;
    #pragma unroll
    for (int j = 0; j < 4; ++j) {
      int o = obase + tx + 16*j;
      float val = acc[i][j];
      if (bias2d) val += bias2d[(r >> 12) * bstride + o];
      out[(size_t)r * ldo + o] = val;
    }
  }
}

// ---------------- split W -> combined [wn; wd] with wd = Wc - Wn ----------------
__global__ __launch_bounds__(256) void prep_w(const float* __restrict__ W,
                                              float* __restrict__ wuv,
                                              int O, int C) {
  int i = blockIdx.x * 256 + threadIdx.x;
  if (i >= O * C) return;
  int o = i / C, c = i - o * C;
  float nn = W[(size_t)o * 2 * C + c];
  float cc = W[(size_t)o * 2 * C + C + c];
  wuv[(size_t)o * C + c] = nn;
  wuv[(size_t)(O + o) * C + c] = cc - nn;
}

// ---------------- single gather: per-(point,channel) max/min + fp64 stats ----------------
__global__ __launch_bounds__(256) void gather_k(const float* __restrict__ u, const float* __restrict__ v,
                                                int lduv, const int* __restrict__ idx,
                                                float* __restrict__ mxb, float* __restrict__ mnb,
                                                double* __restrict__ gsum, double* __restrict__ gsq, int O) {
  __shared__ int sidx[16 * KNN];
  int t = threadIdx.x;
  int p0 = blockIdx.x * 16;
  int b = p0 >> 12;
  const int* ib = idx + (size_t)p0 * KNN;
  for (int i = t; i < 16 * KNN; i += 256) sidx[i] = ib[i];
  __syncthreads();
  int o = t & (O - 1);
  int pl = t / O;
  int ppi = 256 / O;
  const float* ub = u + ((size_t)b << 12) * lduv;
  double S = 0.0, S2 = 0.0;
  for (int p = pl; p < 16; p += ppi) {
    int r = p0 + p;
    float vv = v[(size_t)r * lduv + o];
    float mx = -3.4e38f, mn = 3.4e38f;
    double su = 0.0, su2 = 0.0;
    #pragma unroll
    for (int k = 0; k < KNN; ++k) {
      int m = sidx[p * KNN + k];
      float uvv = ub[(size_t)m * lduv + o];
      mx = fmaxf(mx, uvv);
      mn = fminf(mn, uvv);
      double du = uvv;
      su += du; su2 += du * du;
    }
    mxb[(size_t)r * O + o] = mx;
    mnb[(size_t)r * O + o] = mn;
    double dv = vv;
    S  += su + (double)KNN * dv;
    S2 += su2 + 2.0 * dv * su + (double)KNN * dv * dv;
  }
  atomicAdd(&gsum[o], S);
  atomicAdd(&gsq[o], S2);
}

// ---------------- finalize BN coeffs (fp64) ----------------
__global__ __launch_bounds__(256) void finalize_k(const double* __restrict__ gsum, const double* __restrict__ gsq,
                                                  const float* __restrict__ g, const float* __restrict__ bp,
                                                  float* __restrict__ a, float* __restrict__ bb,
                                                  double invM, int O) {
  int o = blockIdx.x * 256 + threadIdx.x;
  if (o >= O) return;
  double mean = gsum[o] * invM;
  double var = gsq[o] * invM - mean * mean;
  double sc = (double)g[o] / sqrt(var + 1e-5);
  a[o] = (float)sc;
  bb[o] = (float)((double)bp[o] - mean * sc);
}

// ---------------- edge output: elementwise from precomputed max/min ----------------
__global__ __launch_bounds__(256) void edge_out2(const float* __restrict__ v, int lduv,
                                                 const float* __restrict__ mxb, const float* __restrict__ mnb,
                                                 const float* __restrict__ a, const float* __restrict__ bb,
                                                 float* __restrict__ xc, int coff, int O, int lgO) {
  int i = blockIdx.x * 256 + threadIdx.x;
  int r = i >> lgO, o = i & (O - 1);
  float av = a[o];
  float sel = av >= 0.f ? mxb[i] : mnb[i];
  float val = av * (v[(size_t)r * lduv + o] + sel) + bb[o];
  xc[(size_t)r * 512 + coff + o] = lrelu(val);
}

// ---------------- conv5: BN+lrelu then global max over n ----------------
__global__ __launch_bounds__(256) void conv5_max(const float* __restrict__ y,
                                                 const float* __restrict__ a, const float* __restrict__ bb,
                                                 unsigned* __restrict__ gmax) {
  int t = threadIdx.x;
  int b = blockIdx.y;
  int r0 = (b << 12) + blockIdx.x * 64;
  float a0 = a[t], a1 = a[t + 256], b0 = bb[t], b1 = bb[t + 256];
  float m0 = -3.4e38f, m1 = -3.4e38f;
  for (int rr = 0; rr < 64; ++rr) {
    const float* row = y + (size_t)(r0 + rr) * 512;
    float v0 = lrelu(a0 * row[t] + b0);
    float v1 = lrelu(a1 * row[t + 256] + b1);
    m0 = fmaxf(m0, v0);
    m1 = fmaxf(m1, v1);
  }
  atomicMax(&gmax[b * 512 + t], fkey(m0));
  atomicMax(&gmax[b * 512 + t + 256], fkey(m1));
}

// ---------------- gterm[b,o] = sum_c gmax[b,c] * Ws1[o, 512+c] (fp64 acc) ----------------
__global__ __launch_bounds__(256) void gterm_k(const unsigned* __restrict__ gmax,
                                               const float* __restrict__ Ws1,
                                               float* __restrict__ gt) {
  int b = blockIdx.x, o = threadIdx.x;
  double acc = 0.0;
  for (int c = 0; c < 512; ++c)
    acc += (double)funkey(gmax[b * 512 + c]) * (double)Ws1[(size_t)o * 1024 + 512 + c];
  gt[b * 256 + o] = (float)acc;
}

// ---------------- elementwise BN + lrelu ----------------
__global__ __launch_bounds__(256) void bn_apply(const float* __restrict__ y, int ld,
                                                const float* __restrict__ a, const float* __restrict__ bb,
                                                float* __restrict__ out, int ldo, int O) {
  int t = threadIdx.x;
  int o = t & (O - 1);
  int pl = t / O;
  int rpi = 256 / O;
  int r0 = blockIdx.x * 64;
  float av = a[o], bv = bb[o];
  for (int rr = pl; rr < 64; rr += rpi) {
    int r = r0 + rr;
    float val = av * y[(size_t)r * ld + o] + bv;
    out[(size_t)r * ldo + o] = lrelu(val);
  }
}

// ---------------- final 2-channel projection (fp64 acc), output (B,2,N) ----------------
__global__ __launch_bounds__(256) void final_out(const float* __restrict__ h,
                                                 const float* __restrict__ Ws3,
                                                 const float* __restrict__ bias3,
                                                 float* __restrict__ out) {
  int rr = blockIdx.x * 256 + threadIdx.x;
  if (rr >= MROWS) return;
  int b = rr >> 12, n = rr & 4095;
  const float* row = h + (size_t)rr * 128;
  double a0 = 0.0, a1 = 0.0;
  for (int c = 0; c < 128; ++c) {
    double hv = row[c];
    a0 += hv * (double)Ws3[c];
    a1 += hv * (double)Ws3[128 + c];
  }
  out[((size_t)b * 2) * NPTS + n] = (float)(a0 + (double)bias3[0]);
  out[((size_t)b * 2 + 1) * NPTS + n] = (float)(a1 + (double)bias3[1]);
}

extern "C" void kernel_launch(void* const* d_in, const int* in_sizes, int n_in,
                              void* d_out, int out_size, void* d_ws, size_t ws_size,
                              hipStream_t stream) {
  const float* points = (const float*)d_in[0];
  const float* W1 = (const float*)d_in[1];  const float* g1 = (const float*)d_in[2];  const float* b1 = (const float*)d_in[3];
  const float* W2 = (const float*)d_in[4];  const float* g2 = (const float*)d_in[5];  const float* b2 = (const float*)d_in[6];
  const float* W3 = (const float*)d_in[7];  const float* g3 = (const float*)d_in[8];  const float* b3 = (const float*)d_in[9];
  const float* W4 = (const float*)d_in[10]; const float* g4 = (const float*)d_in[11]; const float* b4 = (const float*)d_in[12];
  const float* W5 = (const float*)d_in[13]; const float* g5 = (const float*)d_in[14]; const float* b5 = (const float*)d_in[15];
  const float* Ws1 = (const float*)d_in[16]; const float* gs1 = (const float*)d_in[17]; const float* bs1 = (const float*)d_in[18];
  const float* Ws2 = (const float*)d_in[19]; const float* gs2 = (const float*)d_in[20]; const float* bs2 = (const float*)d_in[21];
  const float* Ws3 = (const float*)d_in[22]; const float* bias3 = (const float*)d_in[23];

  size_t fixedBytes = (size_t)(MROWS*NCAND*4) + (size_t)(MROWS*KNN*4) + (size_t)(MROWS*4)
                    + (size_t)MROWS*512*4 /*uv*/ + (size_t)MROWS*512*4 /*xcb*/ + (512*256*4)
                    + 8*1024 + 4*1024 + NB*512*4 + NB*256*4 + 64*1024;
  int CH = (ws_size >= (size_t)4096 * NPTS * 4 + fixedBytes) ? 4096 : 2048;

  char* p = (char*)d_ws;
  auto carve = [&](size_t nbytes) -> char* {
    char* q = p;
    p += (nbytes + 255) & ~(size_t)255;
    return q;
  };
  float* big  = (float*)carve((size_t)CH * NPTS * 4);   // D batch / y buffers / mx+mn
  int*   candb = (int*)carve((size_t)MROWS * NCAND * 4);
  int*   idxb = (int*)carve((size_t)MROWS * KNN * 4);
  float* xx   = (float*)carve((size_t)MROWS * 4);
  float* uv   = (float*)carve((size_t)MROWS * 512 * 4); // combined u|v (stride 2O)
  float* xcb  = (float*)carve((size_t)MROWS * 512 * 4);
  float* wuv  = (float*)carve(512 * 128 * 4);           // [2O][C] combined weights
  double* gsum = (double*)carve(512 * 8);
  double* gsq  = (double*)carve(512 * 8);
  float* acoef = (float*)carve(512 * 4);
  float* bcoef = (float*)carve(512 * 4);
  unsigned* gmax = (unsigned*)carve(NB * 512 * 4);
  float* gtermb = (float*)carve(NB * 256 * 4);
  float* h1n = uv;                          // uv dead after edges
  float* h2n = uv + (size_t)MROWS * 256;

  auto edge = [&](const float* X, int ldx, int C, int O, int lgO,
                  const float* W, const float* g, const float* bp, int coff) {
    if (C == 3) {
      select3_k<<<MROWS, 256, 0, stream>>>(X, candb);
    } else {
      sqnorm_k<<<MROWS / 256, 256, 0, stream>>>(X, ldx, C, xx);
      if (CH == 4096) {
        for (int b = 0; b < NB; ++b) {
          dist_tri_k<<<528, 256, 0, stream>>>(X + (size_t)b * NPTS * ldx, ldx, C,
                                              xx + b * NPTS, big);
          select_k<<<NPTS, 256, 0, stream>>>(big, candb, b, 0);
        }
      } else {
        for (int b = 0; b < NB; ++b) {
          for (int n0 = 0; n0 < NPTS; n0 += CH) {
            gemm128_k<<<dim3(NPTS / 128, CH / 128), 256, 0, stream>>>(
                X + ((size_t)b * NPTS + n0) * ldx, ldx,
                X + (size_t)b * NPTS * ldx, ldx, C,
                big, NPTS, nullptr, 0,
                xx + b * NPTS + n0, xx + b * NPTS, nullptr, nullptr);
            select_k<<<CH, 256, 0, stream>>>(big, candb, b, n0);
          }
        }
      }
    }
    refine_k<<<MROWS / 4, 256, 0, stream>>>(X, ldx, C, candb, idxb);
    prep_w<<<(O * C + 255) / 256, 256, 0, stream>>>(W, wuv, O, C);
    int O2 = 2 * O;
    if (C % 32 == 0)
      gemm128_k<<<dim3(O2 / 128, MROWS / 128), 256, 0, stream>>>(
          X, ldx, wuv, C, C, uv, O2, nullptr, 0, nullptr, nullptr, nullptr, nullptr);
    else
      gemm_k<<<dim3(O2 / 64, MROWS / 64), 256, 0, stream>>>(X, ldx, wuv, C, uv, O2, nullptr, 0, C);
    hipMemsetAsync(gsum, 0, 512 * 8 * 2, stream);
    float* mxb = big;
    float* mnb = big + (size_t)MROWS * O;
    gather_k<<<MROWS / 16, 256, 0, stream>>>(uv, uv + O, O2, idxb, mxb, mnb, gsum, gsq, O);
    finalize_k<<<(O + 255) / 256, 256, 0, stream>>>(gsum, gsq, g, bp, acoef, bcoef,
                                                    1.0 / ((double)MROWS * KNN), O);
    edge_out2<<<(MROWS * O) / 256, 256, 0, stream>>>(uv + O, O2, mxb, mnb, acoef, bcoef, xcb, coff, O, lgO);
  };

  edge(points,    3,   3,  64, 6, W1, g1, b1, 0);
  edge(xcb,       512, 64, 64, 6, W2, g2, b2, 64);
  edge(xcb + 64,  512, 64, 128, 7, W3, g3, b3, 128);
  edge(xcb + 128, 512, 128, 256, 8, W4, g4, b4, 256);

  // conv5: y5 = xc @ W5^T (stats fused)
  hipMemsetAsync(gsum, 0, 512 * 8 * 2, stream);
  gemm128_k<<<dim3(4, MROWS / 128), 256, 0, stream>>>(xcb, 512, W5, 512, 512, big, 512,
                                                      nullptr, 0, nullptr, nullptr, gsum, gsq);
  finalize_k<<<2, 256, 0, stream>>>(gsum, gsq, g5, b5, acoef, bcoef, 1.0 / MROWS, 512);
  hipMemsetAsync(gmax, 0, NB * 512 * 4, stream);
  conv5_max<<<dim3(NPTS / 64, NB), 256, 0, stream>>>(big, acoef, bcoef, gmax);
  gterm_k<<<NB, 256, 0, stream>>>(gmax, Ws1, gtermb);

  // h1 = lrelu(bn(xc @ Ws1a^T + gterm)) (stats fused)
  hipMemsetAsync(gsum, 0, 512 * 8 * 2, stream);
  gemm128_k<<<dim3(2, MROWS / 128), 256, 0, stream>>>(xcb, 512, Ws1, 1024, 512, big, 256,
                                                      gtermb, 256, nullptr, nullptr, gsum, gsq);
  finalize_k<<<1, 256, 0, stream>>>(gsum, gsq, gs1, bs1, acoef, bcoef, 1.0 / MROWS, 256);
  bn_apply<<<MROWS / 64, 256, 0, stream>>>(big, 256, acoef, bcoef, h1n, 256, 256);

  // h2 = lrelu(bn(h1 @ Ws2^T)) (stats fused)
  hipMemsetAsync(gsum, 0, 512 * 8 * 2, stream);
  gemm128_k<<<dim3(1, MROWS / 128), 256, 0, stream>>>(h1n, 256, Ws2, 256, 256, big, 128,
                                                      nullptr, 0, nullptr, nullptr, gsum, gsq);
  finalize_k<<<1, 256, 0, stream>>>(gsum, gsq, gs2, bs2, acoef, bcoef, 1.0 / MROWS, 128);
  bn_apply<<<MROWS / 64, 256, 0, stream>>>(big, 128, acoef, bcoef, h2n, 128, 128);

  // out = h2 @ Ws3^T + bias3 -> (B,2,N)
  final_out<<<MROWS / 256, 256, 0, stream>>>(h2n, Ws3, bias3, (float*)d_out);
}